// Round 12
// baseline (100.757 us; speedup 1.0000x reference)
//
#include <hip/hip_runtime.h>
#include <math.h>

// 256-point FFT = 16x16 four-step Cooley-Tukey, one batch per 16 lanes.
// MLP fix (rounds 8-11 showed latency-bound at 4.27/6.3 TB/s HBM, and the
// register allocator refuses reg-based prefetch): double-buffered LDS
// prefetch via global_load_lds (DMA holds no VGPRs) with a counted vmcnt
// ledger (m135 oldest-first semantics), one tile in flight ahead of
// compute. Per wave per tile: 8 x global_load_lds_dwordx4 (8 KB = 4
// batches), 32 nt stores. Ledger per iter: +8 loads +32 stores ->
// waits vmcnt(8) t=0, vmcnt(40) mid, vmcnt(32) last.
// 64 KB LDS/block -> 2 blocks/CU -> backend targets 2 waves/EU -> big
// VGPR budget, no spills (round-11 lesson: LDS sizing steers allocator).
// Cache policy: DMA loads default (input stays L3-resident), NT stores.
// Wave-private everything -> no __syncthreads.

#define T_TILES 4   // tiles per block; block = 4 waves x 4 batches/tile

__device__ __forceinline__ void wave_fence() {
    __builtin_amdgcn_wave_barrier();
}

__device__ __forceinline__ void gload16(const float* g, float* l) {
    // 16B per lane: global (per-lane addr) -> LDS (wave-uniform base + lane*16)
    __builtin_amdgcn_global_load_lds(
        (const __attribute__((address_space(1))) void*)g,
        (__attribute__((address_space(3))) void*)l, 16, 0, 0);
}

__device__ __forceinline__ void fft16(float re[16], float im[16]) {
    // 4-bit bit-reversal permutation (swap i < rev(i))
    {
        float tr, ti;
#define SWP(a, b) tr = re[a]; re[a] = re[b]; re[b] = tr; ti = im[a]; im[a] = im[b]; im[b] = ti;
        SWP(1, 8) SWP(2, 4) SWP(3, 12) SWP(5, 10) SWP(7, 14) SWP(11, 13)
#undef SWP
    }
    const float C[8] = { 1.0f,  0.92387953251f,  0.70710678119f,  0.38268343236f,
                         0.0f, -0.38268343236f, -0.70710678119f, -0.92387953251f };
    const float S16[8] = { 0.0f, -0.38268343236f, -0.70710678119f, -0.92387953251f,
                          -1.0f, -0.92387953251f, -0.70710678119f, -0.38268343236f };
#pragma unroll
    for (int s = 1; s <= 4; ++s) {
        const int len = 1 << s;
        const int half = len >> 1;
        const int step = 16 >> s;
#pragma unroll
        for (int i = 0; i < 16; i += len) {
#pragma unroll
            for (int j = 0; j < half; ++j) {
                const float wr = C[j * step];
                const float wi = S16[j * step];
                const int p = i + j;
                const int q = i + j + half;
                const float vr = re[q] * wr - im[q] * wi;
                const float vi = re[q] * wi + im[q] * wr;
                const float ur = re[p], ui = im[p];
                re[p] = ur + vr; im[p] = ui + vi;
                re[q] = ur - vr; im[q] = ui - vi;
            }
        }
    }
}

__global__ __launch_bounds__(256) void fft256_kernel(const float* __restrict__ x,
                                                     float* __restrict__ out) {
    // stage[buf][wave][2048 floats]: 2 x 4 x 8 KB = 64 KB
    __shared__ __align__(16) float stage[2 * 4 * 2048];

    const int tid  = threadIdx.x;
    const int wave = tid >> 6;        // 0..3
    const int lane = tid & 63;
    const int sub  = tid >> 4;        // 0..15: batch-in-tile
    const int t16  = tid & 15;
    const int siw  = sub & 3;         // sub within wave

    const long block_base = (long)blockIdx.x * (T_TILES * 16);

    float* wbuf[2] = { stage + wave * 2048, stage + 8192 + wave * 2048 };

    // ---- Prologue: issue DMA for tiles 0 and 1 (16 loads outstanding)
#pragma unroll
    for (int pt = 0; pt < 2; ++pt) {
        const float* src = x + (block_base + pt * 16 + wave * 4) * 512 + lane * 4;
        float* dst = wbuf[pt];
#pragma unroll
        for (int j = 0; j < 8; ++j) gload16(src + j * 256, dst + j * 256);
    }

#pragma unroll
    for (int t = 0; t < T_TILES; ++t) {
        // Counted wait: oldest 8 (this tile's loads) must have landed.
        // Ledger of newer ops: mid iters = 32 stores + 8 loads = 40.
        if (t == 0)               asm volatile("s_waitcnt vmcnt(8)" ::: "memory");
        else if (t < T_TILES - 1) asm volatile("s_waitcnt vmcnt(40)" ::: "memory");
        else                      asm volatile("s_waitcnt vmcnt(32)" ::: "memory");
        __builtin_amdgcn_sched_barrier(0);

        float* Ls = wbuf[t & 1] + siw * 512;  // this lane's staged batch
        const long bb = block_base + t * 16 + sub;

        float re[16], im[16];
#pragma unroll
        for (int i = 0; i < 16; ++i) re[i] = Ls[t16 + 16 * i];
#pragma unroll
        for (int i = 0; i < 16; ++i) im[i] = Ls[256 + t16 + 16 * i];

        fft16(re, im);  // Y[t16, k2] over n2

        // Twiddle W_256^{t16*k}; imag rows into the (now dead) staging
        // region, real kept in regs. 17-stride tile inside Ls[0..271].
#pragma unroll
        for (int k = 0; k < 16; ++k) {
            float sv, cv;
            __sincosf(-6.283185307179586f * (float)(t16 * k) * (1.0f / 256.0f), &sv, &cv);
            const float tr = re[k] * cv - im[k] * sv;
            const float ti = re[k] * sv + im[k] * cv;
            Ls[17 * t16 + k] = ti;
            re[k] = tr;
        }
        wave_fence();
#pragma unroll
        for (int n = 0; n < 16; ++n) im[n] = Ls[17 * n + t16];   // imag cols out
        wave_fence();
#pragma unroll
        for (int k = 0; k < 16; ++k) Ls[17 * t16 + k] = re[k];   // real rows in
        wave_fence();
#pragma unroll
        for (int n = 0; n < 16; ++n) re[n] = Ls[17 * n + t16];   // real cols out

        fft16(re, im);  // X[t16 + 16*k1] over k1

        float* outr = out + bb * 512;
        float* outi = outr + 256;
#pragma unroll
        for (int k = 0; k < 16; ++k) __builtin_nontemporal_store(re[k], outr + t16 + 16 * k);
#pragma unroll
        for (int k = 0; k < 16; ++k) __builtin_nontemporal_store(im[k], outi + t16 + 16 * k);

        // Issue DMA for tile t+2 into the buffer just freed. Compiler
        // barrier first: the transpose ds_reads above must not be
        // reordered after the DMA issue.
        if (t + 2 < T_TILES) {
            asm volatile("" ::: "memory");
            __builtin_amdgcn_sched_barrier(0);
            const float* src = x + (block_base + (t + 2) * 16 + wave * 4) * 512 + lane * 4;
            float* dst = wbuf[t & 1];
#pragma unroll
            for (int j = 0; j < 8; ++j) gload16(src + j * 256, dst + j * 256);
        }
    }
}

extern "C" void kernel_launch(void* const* d_in, const int* in_sizes, int n_in,
                              void* d_out, int out_size, void* d_ws, size_t ws_size,
                              hipStream_t stream) {
    (void)d_ws; (void)ws_size; (void)n_in; (void)out_size;
    const float* x = (const float*)d_in[0];
    float* out = (float*)d_out;
    const int batches = in_sizes[0] / 512;            // 131072
    const int grid = batches / (T_TILES * 16);        // 2048 blocks
    fft256_kernel<<<grid, 256, 0, stream>>>(x, out);
}